// Round 1
// baseline (297.105 us; speedup 1.0000x reference)
//
#include <hip/hip_runtime.h>

#define NB 65536
#define NH 7
#define NPTS (NB*NH)          // 458752 points (b,h)
#define NROOTS 240
#define NELEM (NPTS*8)        // 3670016

// output layout (flat float32, reference return order)
#define O_QUANT 0
#define O_IDX   3670016
#define O_QERR  4587520
#define O_PROD  4587521      // ODD offset -> not 16B aligned, scalar stores only
#define O_ALIGN 8257537
#define O_FANO  8716289

__device__ inline void wave_block_sum(double* dst, float v) {
  #pragma unroll
  for (int off = 32; off > 0; off >>= 1) v += __shfl_down(v, off, 64);
  if ((threadIdx.x & 63) == 0) atomicAdd(dst, (double)v);
}

__global__ void zero_ws_kernel(double* ws) {
  if (threadIdx.x == 0) { ws[0] = 0.0; ws[1] = 0.0; }
}

__global__ __launch_bounds__(256) void quant_kernel(
    const float* __restrict__ states, const float* __restrict__ roots,
    float* __restrict__ out, double* __restrict__ ws) {
  __shared__ float sroots[NROOTS*8];
  for (int i = threadIdx.x; i < NROOTS*8; i += 256) sroots[i] = roots[i];
  __syncthreads();

  int p = blockIdx.x * 256 + threadIdx.x;   // grid is exact: 1792*256 = NPTS
  float4 xa = ((const float4*)states)[p*2];
  float4 xb = ((const float4*)states)[p*2+1];
  float x[8] = {xa.x, xa.y, xa.z, xa.w, xb.x, xb.y, xb.z, xb.w};
  float qs[8] = {0.f,0.f,0.f,0.f,0.f,0.f,0.f,0.f};
  int idx[2];

  #pragma unroll
  for (int lvl = 0; lvl < 2; ++lvl) {
    float res[8];
    float res2 = 0.f;
    #pragma unroll
    for (int k = 0; k < 8; ++k) { res[k] = x[k] - qs[k]; res2 = fmaf(res[k], res[k], res2); }
    // reference: d2 = (res2 + r2) - 2*dot ; all roots have r2 == 2.0f exactly
    float base = res2 + 2.0f;
    float best = 3.4e38f; int bi = 0;
    for (int r = 0; r < NROOTS; ++r) {
      const float* rt = &sroots[r*8];
      float dot = 0.f;
      #pragma unroll
      for (int k = 0; k < 8; ++k) dot = fmaf(res[k], rt[k], dot);
      float d2 = fmaf(-2.f, dot, base);   // 2*dot is exact, so == base - 2*dot
      d2 = fmaxf(d2, 0.f);
      if (d2 < best) { best = d2; bi = r; }  // strict < == np.argmin first-index
    }
    #pragma unroll
    for (int k = 0; k < 8; ++k) qs[k] += sroots[bi*8+k];
    idx[lvl] = bi;
  }

  ((float4*)(out + O_QUANT))[p*2]   = make_float4(qs[0],qs[1],qs[2],qs[3]);
  ((float4*)(out + O_QUANT))[p*2+1] = make_float4(qs[4],qs[5],qs[6],qs[7]);
  out[O_IDX + p]        = (float)idx[0];
  out[O_IDX + NPTS + p] = (float)idx[1];

  float e = 0.f;
  #pragma unroll
  for (int k = 0; k < 8; ++k) { float d = x[k] - qs[k]; e = fmaf(d, d, e); }
  wave_block_sum(ws + 0, e);
}

__global__ __launch_bounds__(256) void fano_kernel(
    const float* __restrict__ qbuf,
    const int* __restrict__ li, const int* __restrict__ lj, const int* __restrict__ lk,
    float* __restrict__ out, double* __restrict__ ws) {
  int t = blockIdx.x * 256 + threadIdx.x;   // 0..NPTS-1, (b, line)
  int b = t / 7, l = t - b * 7;
  int i = li[l], j = lj[l], kk = lk[l];
  const float* qb = qbuf + (size_t)b * 56;

  float A[8], Bq[8], C[8];
  #pragma unroll
  for (int m = 0; m < 8; ++m) { A[m] = qb[i*8+m]; Bq[m] = qb[j*8+m]; C[m] = qb[kk*8+m]; }

  float a0=A[0],a1=A[1],a2=A[2],a3=A[3], b0=A[4],b1=A[5],b2=A[6],b3=A[7];
  float c0=Bq[0],c1=Bq[1],c2=Bq[2],c3=Bq[3], d0=Bq[4],d1=Bq[5],d2q=Bq[6],d3=Bq[7];

  // t1 = quat_mul(a, c)
  float t1w = a0*c0 - a1*c1 - a2*c2 - a3*c3;
  float t1x = a0*c1 + a1*c0 + a2*c3 - a3*c2;
  float t1y = a0*c2 - a1*c3 + a2*c0 + a3*c1;
  float t1z = a0*c3 + a1*c2 - a2*c1 + a3*c0;
  // t2 = quat_mul(conj(d), b), conj(d) = (d0,-d1,-d2,-d3)
  float q0=d0, q1=-d1, q2=-d2q, q3=-d3;
  float t2w = q0*b0 - q1*b1 - q2*b2 - q3*b3;
  float t2x = q0*b1 + q1*b0 + q2*b3 - q3*b2;
  float t2y = q0*b2 - q1*b3 + q2*b0 + q3*b1;
  float t2z = q0*b3 + q1*b2 - q2*b1 + q3*b0;
  // t3 = quat_mul(d, a)
  float t3w = d0*a0 - d1*a1 - d2q*a2 - d3*a3;
  float t3x = d0*a1 + d1*a0 + d2q*a3 - d3*a2;
  float t3y = d0*a2 - d1*a3 + d2q*a0 + d3*a1;
  float t3z = d0*a3 + d1*a2 - d2q*a1 + d3*a0;
  // t4 = quat_mul(b, conj(c)), conj(c) = (c0,-c1,-c2,-c3)
  float p0=c0, p1=-c1, p2=-c2, p3=-c3;
  float t4w = b0*p0 - b1*p1 - b2*p2 - b3*p3;
  float t4x = b0*p1 + b1*p0 + b2*p3 - b3*p2;
  float t4y = b0*p2 - b1*p3 + b2*p0 + b3*p1;
  float t4z = b0*p3 + b1*p2 - b2*p1 + b3*p0;

  float P[8] = {t1w-t2w, t1x-t2x, t1y-t2y, t1z-t2z,
                t3w+t4w, t3x+t4x, t3y+t4y, t3z+t4z};

  float dot = 0.f, np2 = 0.f, nc2 = 0.f;
  #pragma unroll
  for (int m = 0; m < 8; ++m) {
    dot = fmaf(P[m], C[m], dot);
    np2 = fmaf(P[m], P[m], np2);
    nc2 = fmaf(C[m], C[m], nc2);
  }
  float denom = fmaxf(sqrtf(np2) * sqrtf(nc2), 1e-8f);
  float align = dot / denom;

  // O_PROD is not 16B-aligned -> scalar stores
  #pragma unroll
  for (int m = 0; m < 8; ++m) out[O_PROD + (size_t)t*8 + m] = P[m];
  out[O_ALIGN + t] = align;

  float contrib = 1.f - fminf(fmaxf(align, -1.f), 1.f);
  wave_block_sum(ws + 1, contrib);
}

__global__ void finalize_kernel(const double* __restrict__ ws, float* __restrict__ out) {
  if (threadIdx.x == 0) {
    out[O_QERR] = (float)(ws[0] / (double)NELEM);
    double f = 0.5 * (ws[1] / (double)NPTS);
    f = fmin(fmax(f, 0.0), 1.0);
    out[O_FANO] = (float)f;
  }
}

extern "C" void kernel_launch(void* const* d_in, const int* in_sizes, int n_in,
                              void* d_out, int out_size, void* d_ws, size_t ws_size,
                              hipStream_t stream) {
  const float* states = (const float*)d_in[0];
  const float* roots  = (const float*)d_in[1];
  const int*   li     = (const int*)d_in[2];
  const int*   lj     = (const int*)d_in[3];
  const int*   lk     = (const int*)d_in[4];
  float*  out = (float*)d_out;
  double* ws  = (double*)d_ws;

  zero_ws_kernel<<<1, 64, 0, stream>>>(ws);
  quant_kernel<<<NPTS/256, 256, 0, stream>>>(states, roots, out, ws);
  fano_kernel<<<NPTS/256, 256, 0, stream>>>(out + O_QUANT, li, lj, lk, out, ws);
  finalize_kernel<<<1, 64, 0, stream>>>(ws, out);
}

// Round 2
// 132.104 us; speedup vs baseline: 2.2490x; 2.2490x over previous
//
#include <hip/hip_runtime.h>

#define NB 65536
#define NH 7
#define NPTS (NB*NH)          // 458752 points (b,h)
#define NELEM (NPTS*8)        // 3670016

// output layout (flat float32, reference return order)
#define O_QUANT 0
#define O_IDX   3670016
#define O_QERR  4587520
#define O_PROD  4587521      // ODD offset -> not 16B aligned, scalar stores only
#define O_ALIGN 8257537
#define O_FANO  8716289

__device__ inline float wave_sum(float v) {
  #pragma unroll
  for (int off = 32; off > 0; off >>= 1) v += __shfl_down(v, off, 64);
  return v;
}

// one double atomic per block
__device__ inline void block_sum(double* dst, float v, float* wred) {
  float w = wave_sum(v);
  int lane = threadIdx.x & 63, wid = threadIdx.x >> 6;
  if (lane == 0) wred[wid] = w;
  __syncthreads();
  if (threadIdx.x == 0) {
    double s = (double)wred[0] + (double)wred[1] + (double)wred[2] + (double)wred[3];
    atomicAdd(dst, s);
  }
}

__global__ void zero_ws_kernel(double* ws) {
  if (threadIdx.x == 0) { ws[0] = 0.0; ws[1] = 0.0; }
}

// Analytic E8 nearest-root decoder, matching np.argmin first-index tie semantics
// at the class/pattern level (ulp-scale d2 collapses accepted; dataset has none
// at the ulp scale per round-1 absmax=0.0 with a differently-rounded dot).
__global__ __launch_bounds__(256) void quant_kernel(
    const float* __restrict__ states,
    float* __restrict__ out, double* __restrict__ ws) {
  __shared__ float wred[4];
  int p = blockIdx.x * 256 + threadIdx.x;   // grid exact: 1792*256 = NPTS
  float4 xa = ((const float4*)states)[p*2];
  float4 xb = ((const float4*)states)[p*2+1];
  float x[8] = {xa.x, xa.y, xa.z, xa.w, xb.x, xb.y, xb.z, xb.w};
  float qs[8] = {0.f,0.f,0.f,0.f,0.f,0.f,0.f,0.f};
  int idxs[2];

  #pragma unroll
  for (int lvl = 0; lvl < 2; ++lvl) {
    float res[8], ab[8];
    float res2 = 0.f;
    unsigned nb = 0;            // minus-sign pattern: bit (7-k) set iff res[k] < 0
    #pragma unroll
    for (int k = 0; k < 8; ++k) {
      res[k] = x[k] - qs[k];
      res2 = fmaf(res[k], res[k], res2);
      ab[k] = fabsf(res[k]);
      nb |= (res[k] < 0.f) ? (1u << (7 - k)) : 0u;
    }
    float base = res2 + 2.0f;   // all roots have r2 == 2.0f exactly

    // ---- Type I: top-2 |res| (strict > => first-index on ties) ----
    float m1 = -1.f, m2 = -1.f;
    int i1 = 0, i2 = 0; unsigned s1 = 0, s2 = 0;
    #pragma unroll
    for (int k = 0; k < 8; ++k) {
      float a = ab[k]; unsigned s = (res[k] < 0.f) ? 1u : 0u;
      bool g1 = a > m1;
      bool g2 = a > m2;
      float nm2 = g1 ? m1 : (g2 ? a : m2);
      int   ni2 = g1 ? i1 : (g2 ? k : i2);
      unsigned ns2 = g1 ? s1 : (g2 ? s : s2);
      m2 = nm2; i2 = ni2; s2 = ns2;
      m1 = g1 ? a : m1; i1 = g1 ? k : i1; s1 = g1 ? s : s1;
    }
    int i = min(i1, i2), j = max(i1, i2);
    unsigned si = (i1 < i2) ? s1 : s2;
    unsigned sj = (i1 < i2) ? s2 : s1;
    float dotI = m1 + m2;
    int pair_idx = ((i * (15 - i)) >> 1) + (j - i - 1);
    int idxI = 4 * pair_idx + (int)(2u * si + sj);

    // ---- Type II: signs = sign(res), fix parity by flipping min |res| ----
    float sum = ((ab[0]+ab[1]) + (ab[2]+ab[3])) + ((ab[4]+ab[5]) + (ab[6]+ab[7]));
    float half = 0.5f * sum;
    unsigned par = __popc(nb) & 1u;
    float mm = 3.4e38f; unsigned bn = 0xFFu;
    #pragma unroll
    for (int k = 0; k < 8; ++k) {
      unsigned nk = nb ^ (1u << (7 - k));
      bool better = (ab[k] < mm) || (ab[k] == mm && nk < bn);
      mm = better ? ab[k] : mm;
      bn = better ? nk : bn;
    }
    float dotII = par ? (half - mm) : half;
    unsigned nf = par ? bn : nb;
    int idxII = 112 + (int)(nf >> 1);

    // ---- compare in the reference's d2 space ----
    float d2I  = fmaxf(fmaf(-2.f, dotI,  base), 0.f);
    float d2II = fmaxf(fmaf(-2.f, dotII, base), 0.f);
    bool useII = d2II < d2I;          // strict: type-I (lower index) wins ties
    idxs[lvl] = useII ? idxII : idxI;

    #pragma unroll
    for (int k = 0; k < 8; ++k) {
      float rII = ((nf >> (7 - k)) & 1u) ? -0.5f : 0.5f;
      float rI = 0.f;
      rI = (k == i) ? (si ? -1.f : 1.f) : rI;
      rI = (k == j) ? (sj ? -1.f : 1.f) : rI;
      qs[k] += useII ? rII : rI;
    }
  }

  ((float4*)(out + O_QUANT))[p*2]   = make_float4(qs[0],qs[1],qs[2],qs[3]);
  ((float4*)(out + O_QUANT))[p*2+1] = make_float4(qs[4],qs[5],qs[6],qs[7]);
  out[O_IDX + p]        = (float)idxs[0];
  out[O_IDX + NPTS + p] = (float)idxs[1];

  float e = 0.f;
  #pragma unroll
  for (int k = 0; k < 8; ++k) { float d = x[k] - qs[k]; e = fmaf(d, d, e); }
  block_sum(ws + 0, e, wred);
}

__global__ __launch_bounds__(256) void fano_kernel(
    const float* __restrict__ qbuf,
    const int* __restrict__ li, const int* __restrict__ lj, const int* __restrict__ lk,
    float* __restrict__ out, double* __restrict__ ws) {
  __shared__ float wred[4];
  int t = blockIdx.x * 256 + threadIdx.x;   // 0..NPTS-1, (b, line)
  int b = t / 7, l = t - b * 7;
  int i = li[l], j = lj[l], kk = lk[l];
  const float* qb = qbuf + (size_t)b * 56;

  float A[8], Bq[8], C[8];
  #pragma unroll
  for (int m = 0; m < 8; ++m) { A[m] = qb[i*8+m]; Bq[m] = qb[j*8+m]; C[m] = qb[kk*8+m]; }

  float a0=A[0],a1=A[1],a2=A[2],a3=A[3], b0=A[4],b1=A[5],b2=A[6],b3=A[7];
  float c0=Bq[0],c1=Bq[1],c2=Bq[2],c3=Bq[3], d0=Bq[4],d1=Bq[5],d2q=Bq[6],d3=Bq[7];

  // t1 = quat_mul(a, c)
  float t1w = a0*c0 - a1*c1 - a2*c2 - a3*c3;
  float t1x = a0*c1 + a1*c0 + a2*c3 - a3*c2;
  float t1y = a0*c2 - a1*c3 + a2*c0 + a3*c1;
  float t1z = a0*c3 + a1*c2 - a2*c1 + a3*c0;
  // t2 = quat_mul(conj(d), b)
  float q0=d0, q1=-d1, q2=-d2q, q3=-d3;
  float t2w = q0*b0 - q1*b1 - q2*b2 - q3*b3;
  float t2x = q0*b1 + q1*b0 + q2*b3 - q3*b2;
  float t2y = q0*b2 - q1*b3 + q2*b0 + q3*b1;
  float t2z = q0*b3 + q1*b2 - q2*b1 + q3*b0;
  // t3 = quat_mul(d, a)
  float t3w = d0*a0 - d1*a1 - d2q*a2 - d3*a3;
  float t3x = d0*a1 + d1*a0 + d2q*a3 - d3*a2;
  float t3y = d0*a2 - d1*a3 + d2q*a0 + d3*a1;
  float t3z = d0*a3 + d1*a2 - d2q*a1 + d3*a0;
  // t4 = quat_mul(b, conj(c))
  float p0=c0, p1=-c1, p2=-c2, p3=-c3;
  float t4w = b0*p0 - b1*p1 - b2*p2 - b3*p3;
  float t4x = b0*p1 + b1*p0 + b2*p3 - b3*p2;
  float t4y = b0*p2 - b1*p3 + b2*p0 + b3*p1;
  float t4z = b0*p3 + b1*p2 - b2*p1 + b3*p0;

  float P[8] = {t1w-t2w, t1x-t2x, t1y-t2y, t1z-t2z,
                t3w+t4w, t3x+t4x, t3y+t4y, t3z+t4z};

  float dot = 0.f, np2 = 0.f, nc2 = 0.f;
  #pragma unroll
  for (int m = 0; m < 8; ++m) {
    dot = fmaf(P[m], C[m], dot);
    np2 = fmaf(P[m], P[m], np2);
    nc2 = fmaf(C[m], C[m], nc2);
  }
  float denom = fmaxf(sqrtf(np2) * sqrtf(nc2), 1e-8f);
  float align = dot / denom;

  // O_PROD is not 16B-aligned -> scalar stores
  #pragma unroll
  for (int m = 0; m < 8; ++m) out[O_PROD + (size_t)t*8 + m] = P[m];
  out[O_ALIGN + t] = align;

  float contrib = 1.f - fminf(fmaxf(align, -1.f), 1.f);
  block_sum(ws + 1, contrib, wred);
}

__global__ void finalize_kernel(const double* __restrict__ ws, float* __restrict__ out) {
  if (threadIdx.x == 0) {
    out[O_QERR] = (float)(ws[0] / (double)NELEM);
    double f = 0.5 * (ws[1] / (double)NPTS);
    f = fmin(fmax(f, 0.0), 1.0);
    out[O_FANO] = (float)f;
  }
}

extern "C" void kernel_launch(void* const* d_in, const int* in_sizes, int n_in,
                              void* d_out, int out_size, void* d_ws, size_t ws_size,
                              hipStream_t stream) {
  const float* states = (const float*)d_in[0];
  const int*   li     = (const int*)d_in[2];
  const int*   lj     = (const int*)d_in[3];
  const int*   lk     = (const int*)d_in[4];
  float*  out = (float*)d_out;
  double* ws  = (double*)d_ws;

  zero_ws_kernel<<<1, 64, 0, stream>>>(ws);
  quant_kernel<<<NPTS/256, 256, 0, stream>>>(states, out, ws);
  fano_kernel<<<NPTS/256, 256, 0, stream>>>(out + O_QUANT, li, lj, lk, out, ws);
  finalize_kernel<<<1, 64, 0, stream>>>(ws, out);
}

// Round 3
// 93.194 us; speedup vs baseline: 3.1880x; 1.4175x over previous
//
#include <hip/hip_runtime.h>

#define NB 65536
#define NH 7
#define NPTS (NB*NH)          // 458752 points (b,h)
#define NELEM (NPTS*8)        // 3670016

// output layout (flat float32, reference return order)
#define O_QUANT 0
#define O_IDX   3670016
#define O_QERR  4587520
#define O_PROD  4587521      // ODD offset -> not 16B aligned, scalar stores only
#define O_ALIGN 8257537
#define O_FANO  8716289

#define BPB  64               // batches per block
#define TPB  448              // = BPB*7 threads, 7 waves
#define ROWP 57               // padded row stride (56 data + 1), odd -> conflict-free
#define NBLK (NB/BPB)         // 1024 blocks
#define NWPART (NBLK*7)       // 7168 wave partials per channel

__device__ inline float wave_sum(float v) {
  #pragma unroll
  for (int off = 32; off > 0; off >>= 1) v += __shfl_down(v, off, 64);
  return v;
}

// One thread per (b,h). 64 batches staged per block through LDS.
// Quant (analytic E8 decoder, ulp-faithful to reference: round-2 absmax 0.0),
// then fano lines read the 7 quantized heads of each batch from LDS.
__global__ __launch_bounds__(TPB) void fused_kernel(
    const float* __restrict__ states,
    const int* __restrict__ li, const int* __restrict__ lj, const int* __restrict__ lk,
    float* __restrict__ out, float* __restrict__ ws) {
  __shared__ float sm[BPB * ROWP];
  const int t = threadIdx.x;
  const int B0 = blockIdx.x * BPB;
  const size_t gbase = (size_t)B0 * 56;          // flat float offset of this block's 64 batches

  // ---- stage states -> LDS, coalesced float4 (896 float4 / block) ----
  {
    const float4* src = (const float4*)(states + gbase);   // 16B aligned: gbase % 4 == 0
    #pragma unroll
    for (int rep = 0; rep < 2; ++rep) {
      int i4 = t + rep * TPB;                    // 0..895
      float4 v = src[i4];
      int f = 4 * i4;
      int row = f / 56, k = f - 56 * row;        // float4 never crosses a row (56 % 4 == 0)
      float* d = &sm[row * ROWP + k];
      d[0] = v.x; d[1] = v.y; d[2] = v.z; d[3] = v.w;
    }
  }
  __syncthreads();

  const int bl = t / 7, h = t - bl * 7;          // local batch, head
  const int P = B0 * 7 + t;                      // global point index (b*7+h)
  float* myrow = &sm[bl * ROWP + h * 8];

  float x[8];
  #pragma unroll
  for (int k = 0; k < 8; ++k) x[k] = myrow[k];

  float qs[8] = {0.f,0.f,0.f,0.f,0.f,0.f,0.f,0.f};
  int idxs[2];

  #pragma unroll
  for (int lvl = 0; lvl < 2; ++lvl) {
    float res[8], ab[8];
    float res2 = 0.f;
    unsigned nb = 0;            // minus-sign pattern: bit (7-k) set iff res[k] < 0
    #pragma unroll
    for (int k = 0; k < 8; ++k) {
      res[k] = x[k] - qs[k];
      res2 = fmaf(res[k], res[k], res2);
      ab[k] = fabsf(res[k]);
      nb |= (res[k] < 0.f) ? (1u << (7 - k)) : 0u;
    }
    float base = res2 + 2.0f;   // all roots have r2 == 2.0f exactly

    // ---- Type I: top-2 |res| (strict > => first-index on ties) ----
    float m1 = -1.f, m2 = -1.f;
    int i1 = 0, i2 = 0; unsigned s1 = 0, s2 = 0;
    #pragma unroll
    for (int k = 0; k < 8; ++k) {
      float a = ab[k]; unsigned s = (res[k] < 0.f) ? 1u : 0u;
      bool g1 = a > m1;
      bool g2 = a > m2;
      float nm2 = g1 ? m1 : (g2 ? a : m2);
      int   ni2 = g1 ? i1 : (g2 ? k : i2);
      unsigned ns2 = g1 ? s1 : (g2 ? s : s2);
      m2 = nm2; i2 = ni2; s2 = ns2;
      m1 = g1 ? a : m1; i1 = g1 ? k : i1; s1 = g1 ? s : s1;
    }
    int i = min(i1, i2), j = max(i1, i2);
    unsigned si = (i1 < i2) ? s1 : s2;
    unsigned sj = (i1 < i2) ? s2 : s1;
    float dotI = m1 + m2;
    int pair_idx = ((i * (15 - i)) >> 1) + (j - i - 1);
    int idxI = 4 * pair_idx + (int)(2u * si + sj);

    // ---- Type II: signs = sign(res), fix parity by flipping min |res| ----
    float sum = ((ab[0]+ab[1]) + (ab[2]+ab[3])) + ((ab[4]+ab[5]) + (ab[6]+ab[7]));
    float half = 0.5f * sum;
    unsigned par = __popc(nb) & 1u;
    float mm = 3.4e38f; unsigned bn = 0xFFu;
    #pragma unroll
    for (int k = 0; k < 8; ++k) {
      unsigned nk = nb ^ (1u << (7 - k));
      bool better = (ab[k] < mm) || (ab[k] == mm && nk < bn);
      mm = better ? ab[k] : mm;
      bn = better ? nk : bn;
    }
    float dotII = par ? (half - mm) : half;
    unsigned nf = par ? bn : nb;
    int idxII = 112 + (int)(nf >> 1);

    // ---- compare in the reference's d2 space ----
    float d2I  = fmaxf(fmaf(-2.f, dotI,  base), 0.f);
    float d2II = fmaxf(fmaf(-2.f, dotII, base), 0.f);
    bool useII = d2II < d2I;          // strict: type-I (lower index) wins ties
    idxs[lvl] = useII ? idxII : idxI;

    #pragma unroll
    for (int k = 0; k < 8; ++k) {
      float rII = ((nf >> (7 - k)) & 1u) ? -0.5f : 0.5f;
      float rI = 0.f;
      rI = (k == i) ? (si ? -1.f : 1.f) : rI;
      rI = (k == j) ? (sj ? -1.f : 1.f) : rI;
      qs[k] += useII ? rII : rI;
    }
  }

  // q_err partial (uses x before LDS overwrite; same-thread, no barrier needed)
  float e = 0.f;
  #pragma unroll
  for (int k = 0; k < 8; ++k) { float d = x[k] - qs[k]; e = fmaf(d, d, e); }

  // write qs back in place (each thread owns its 8 slots)
  #pragma unroll
  for (int k = 0; k < 8; ++k) myrow[k] = qs[k];

  // idx store: consecutive threads -> consecutive addresses
  out[O_IDX + P]        = (float)idxs[0];
  out[O_IDX + NPTS + P] = (float)idxs[1];

  __syncthreads();   // all qs visible in LDS

  // ---- coalesced quant write (float4 from LDS) ----
  {
    float4* dst = (float4*)(out + O_QUANT + gbase);
    #pragma unroll
    for (int rep = 0; rep < 2; ++rep) {
      int i4 = t + rep * TPB;
      int f = 4 * i4;
      int row = f / 56, k = f - 56 * row;
      const float* s = &sm[row * ROWP + k];
      dst[i4] = make_float4(s[0], s[1], s[2], s[3]);
    }
  }

  // ---- fano: thread t = (bl, line h) reads heads i,j,k of batch bl from LDS ----
  const int l = h;
  const int hi = li[l], hj = lj[l], hk = lk[l];
  const float* brow = &sm[bl * ROWP];

  float A[8], Bq[8], C[8];
  #pragma unroll
  for (int m = 0; m < 8; ++m) { A[m] = brow[hi*8+m]; Bq[m] = brow[hj*8+m]; C[m] = brow[hk*8+m]; }

  float a0=A[0],a1=A[1],a2=A[2],a3=A[3], b0=A[4],b1=A[5],b2=A[6],b3=A[7];
  float c0=Bq[0],c1=Bq[1],c2=Bq[2],c3=Bq[3], d0=Bq[4],d1=Bq[5],d2q=Bq[6],d3=Bq[7];

  // t1 = quat_mul(a, c)
  float t1w = a0*c0 - a1*c1 - a2*c2 - a3*c3;
  float t1x = a0*c1 + a1*c0 + a2*c3 - a3*c2;
  float t1y = a0*c2 - a1*c3 + a2*c0 + a3*c1;
  float t1z = a0*c3 + a1*c2 - a2*c1 + a3*c0;
  // t2 = quat_mul(conj(d), b)
  float q0=d0, q1=-d1, q2=-d2q, q3=-d3;
  float t2w = q0*b0 - q1*b1 - q2*b2 - q3*b3;
  float t2x = q0*b1 + q1*b0 + q2*b3 - q3*b2;
  float t2y = q0*b2 - q1*b3 + q2*b0 + q3*b1;
  float t2z = q0*b3 + q1*b2 - q2*b1 + q3*b0;
  // t3 = quat_mul(d, a)
  float t3w = d0*a0 - d1*a1 - d2q*a2 - d3*a3;
  float t3x = d0*a1 + d1*a0 + d2q*a3 - d3*a2;
  float t3y = d0*a2 - d1*a3 + d2q*a0 + d3*a1;
  float t3z = d0*a3 + d1*a2 - d2q*a1 + d3*a0;
  // t4 = quat_mul(b, conj(c))
  float p0=c0, p1=-c1, p2=-c2, p3=-c3;
  float t4w = b0*p0 - b1*p1 - b2*p2 - b3*p3;
  float t4x = b0*p1 + b1*p0 + b2*p3 - b3*p2;
  float t4y = b0*p2 - b1*p3 + b2*p0 + b3*p1;
  float t4z = b0*p3 + b1*p2 - b2*p1 + b3*p0;

  float Pv[8] = {t1w-t2w, t1x-t2x, t1y-t2y, t1z-t2z,
                 t3w+t4w, t3x+t4x, t3y+t4y, t3z+t4z};

  float dot = 0.f, np2 = 0.f, nc2 = 0.f;
  #pragma unroll
  for (int m = 0; m < 8; ++m) {
    dot = fmaf(Pv[m], C[m], dot);
    np2 = fmaf(Pv[m], Pv[m], np2);
    nc2 = fmaf(C[m], C[m], nc2);
  }
  float denom = fmaxf(sqrtf(np2) * sqrtf(nc2), 1e-8f);
  float align = dot / denom;

  out[O_ALIGN + P] = align;                       // coalesced
  float contrib = 1.f - fminf(fmaxf(align, -1.f), 1.f);

  __syncthreads();   // everyone done READING qs from LDS

  // stage P into LDS (thread's own 8 slots), then coalesced flat copy
  #pragma unroll
  for (int m = 0; m < 8; ++m) myrow[m] = Pv[m];
  __syncthreads();

  {
    float* dst = out + O_PROD + gbase;            // odd global offset -> scalar stores
    #pragma unroll
    for (int rep = 0; rep < 8; ++rep) {
      int f = t + rep * TPB;                      // 0..3583
      int row = f / 56, k = f - 56 * row;
      dst[f] = sm[row * ROWP + k];
    }
  }

  // ---- per-wave partial sums, no atomics ----
  float ew = wave_sum(e);
  float fw = wave_sum(contrib);
  int lane = t & 63, w = t >> 6;                  // 7 waves
  if (lane == 0) {
    int slot = blockIdx.x * 7 + w;
    ws[2*slot]   = ew;
    ws[2*slot+1] = fw;
  }
}

__global__ __launch_bounds__(1024) void finalize_kernel(
    const float* __restrict__ ws, float* __restrict__ out) {
  __shared__ double we[16], wf[16];
  double e = 0.0, f = 0.0;
  for (int i = threadIdx.x; i < NWPART; i += 1024) {
    e += (double)ws[2*i];
    f += (double)ws[2*i+1];
  }
  #pragma unroll
  for (int off = 32; off > 0; off >>= 1) {
    e += __shfl_down(e, off, 64);
    f += __shfl_down(f, off, 64);
  }
  int w = threadIdx.x >> 6, lane = threadIdx.x & 63;
  if (lane == 0) { we[w] = e; wf[w] = f; }
  __syncthreads();
  if (threadIdx.x == 0) {
    double E = 0.0, F = 0.0;
    #pragma unroll
    for (int i = 0; i < 16; ++i) { E += we[i]; F += wf[i]; }
    out[O_QERR] = (float)(E / (double)NELEM);
    double g = 0.5 * (F / (double)NPTS);
    out[O_FANO] = (float)fmin(fmax(g, 0.0), 1.0);
  }
}

extern "C" void kernel_launch(void* const* d_in, const int* in_sizes, int n_in,
                              void* d_out, int out_size, void* d_ws, size_t ws_size,
                              hipStream_t stream) {
  const float* states = (const float*)d_in[0];
  const int*   li     = (const int*)d_in[2];
  const int*   lj     = (const int*)d_in[3];
  const int*   lk     = (const int*)d_in[4];
  float*  out = (float*)d_out;
  float*  ws  = (float*)d_ws;

  fused_kernel<<<NBLK, TPB, 0, stream>>>(states, li, lj, lk, out, ws);
  finalize_kernel<<<1, 1024, 0, stream>>>(ws, out);
}